// Round 3
// baseline (440.016 us; speedup 1.0000x reference)
//
#include <hip/hip_runtime.h>

#define NV 32        // 32 float4 per 128-float row; 32 lanes cooperate on one row
#define UNROLL 4     // independent gather chains in flight per thread

typedef float f32x4 __attribute__((ext_vector_type(4)));
typedef int   i32x2 __attribute__((ext_vector_type(2)));

__global__ __launch_bounds__(256) void ProdLayer_fwd(
    const f32x4* __restrict__ node4,    // node_mars [NUM_INPUT_NODES][NV] f32x4
    const int*   __restrict__ nids,     // [num_nodes]
    const i32x2* __restrict__ cids2,    // [num_nodes] pairs (cids[n][0], cids[n][1])
    f32x4*       __restrict__ out4,     // element_mars [NUM_ELS][NV] f32x4
    int num_nodes)
{
    // Reserved dummy row 0: reference leaves it zero; d_out is poisoned 0xAA.
    if (blockIdx.x == 0 && threadIdx.x < NV) {
        f32x4 z = {0.f, 0.f, 0.f, 0.f};
        out4[threadIdx.x] = z;
    }

    const int tid     = blockIdx.x * blockDim.x + threadIdx.x;
    const int t       = tid & 31;                         // f32x4 slot in row
    const int n0      = tid >> 5;                         // first node for this 32-lane group
    const int nstride = (gridDim.x * blockDim.x) >> 5;    // 16384 nodes per sweep

    int n = n0;
    // Main loop: batch indices for UNROLL rows, then issue all gathers so
    // 2*UNROLL independent 512B reads are in flight per half-wave.
    for (; n + (UNROLL - 1) * nstride < num_nodes; n += UNROLL * nstride) {
        int   o[UNROLL];
        i32x2 c[UNROLL];
        #pragma unroll
        for (int k = 0; k < UNROLL; ++k) {
            const int nk = n + k * nstride;
            o[k] = __builtin_nontemporal_load(&nids[nk]);   // read-once streams:
            c[k] = __builtin_nontemporal_load(&cids2[nk]);  // don't pollute caches
        }
        f32x4 a[UNROLL], b[UNROLL];
        #pragma unroll
        for (int k = 0; k < UNROLL; ++k) a[k] = node4[c[k].x * NV + t];
        #pragma unroll
        for (int k = 0; k < UNROLL; ++k) b[k] = node4[c[k].y * NV + t];
        #pragma unroll
        for (int k = 0; k < UNROLL; ++k) {
            const f32x4 r = a[k] + b[k];
            // NT store: 134MB write-once stream — keep L3 for the gather table.
            __builtin_nontemporal_store(r, &out4[o[k] * NV + t]);
        }
    }
    // Tail (not taken for 262144/16384=16 iters, kept for generality)
    for (; n < num_nodes; n += nstride) {
        const int   o = nids[n];
        const i32x2 c = cids2[n];
        const f32x4 r = node4[c.x * NV + t] + node4[c.y * NV + t];
        __builtin_nontemporal_store(r, &out4[o * NV + t]);
    }
}

extern "C" void kernel_launch(void* const* d_in, const int* in_sizes, int n_in,
                              void* d_out, int out_size, void* d_ws, size_t ws_size,
                              hipStream_t stream) {
    const f32x4* node4 = (const f32x4*)d_in[0];
    // d_in[1] = element_mars input (zeros); only row 0 survives -> written directly.
    const int*   nids  = (const int*)d_in[2];
    const i32x2* cids2 = (const i32x2*)d_in[3];
    f32x4* out4 = (f32x4*)d_out;

    const int num_nodes = in_sizes[2];  // 262144

    const int block = 256;
    const int grid  = 2048;  // 8192 waves = exactly fills 256 CU x 32 waves
    ProdLayer_fwd<<<grid, block, 0, stream>>>(node4, nids, cids2, out4, num_nodes);
}